// Round 2
// baseline (205.092 us; speedup 1.0000x reference)
//
#include <hip/hip_runtime.h>
#include <stdint.h>

// Problem constants (fixed by the reference)
#define NV    8192   // variables
#define NC    4096   // checks
#define DC    6      // edges per check
#define DV    3      // edges per variable
#define NE    24576  // edges
#define NITER 5
#define BATCH 2048

// ---------------------------------------------------------------------------
// Setup kernels: build per-var edge list (deterministic via sort) and packed
// column table, all in d_ws. Rebuilt every launch (cheap, deterministic).
// ---------------------------------------------------------------------------

__global__ void build_v2e(const int* __restrict__ cols, int* __restrict__ cnt,
                          unsigned short* __restrict__ v2e_tmp) {
  int e = blockIdx.x * blockDim.x + threadIdx.x;
  if (e >= NE) return;
  int v = cols[e];
  int s = atomicAdd(&cnt[v], 1);
  v2e_tmp[v * DV + s] = (unsigned short)e;
}

__global__ void sort_transform(const unsigned short* __restrict__ v2e_tmp,
                               ushort4* __restrict__ v2e) {
  int v = blockIdx.x * blockDim.x + threadIdx.x;
  if (v >= NV) return;
  int a = v2e_tmp[v * 3 + 0];
  int b = v2e_tmp[v * 3 + 1];
  int c = v2e_tmp[v * 3 + 2];
  int t;
  if (a > b) { t = a; a = b; b = t; }
  if (b > c) { t = b; b = c; c = t; }
  if (a > b) { t = a; a = b; b = t; }
  // transform edge index -> slot-major LDS element index: (e%6)*NC + e/6
  // (a<b<c preserved order-wise for the np.add.at association: e order)
  int ca = a / DC, cb = b / DC, cc = c / DC;
  ushort4 r;
  r.x = (unsigned short)((a - ca * DC) * NC + ca);
  r.y = (unsigned short)((b - cb * DC) * NC + cb);
  r.z = (unsigned short)((c - cc * DC) * NC + cc);
  r.w = 0;
  v2e[v] = r;
}

// colp32[k*NC + c] packs H_cols[6c+2k] | H_cols[6c+2k+1]<<16, k=0..2
__global__ void pack_cols(const int* __restrict__ cols, unsigned int* __restrict__ colp32) {
  int t = blockIdx.x * blockDim.x + threadIdx.x;
  if (t >= NC * 3) return;
  int k = t / NC;
  int c = t - k * NC;
  unsigned int lo = (unsigned int)cols[c * DC + 2 * k + 0] & 0xffffu;
  unsigned int hi = (unsigned int)cols[c * DC + 2 * k + 1] & 0xffffu;
  colp32[k * NC + c] = lo | (hi << 16);
}

// ---------------------------------------------------------------------------
// Main fused decoder: one workgroup per batch element, full state in LDS.
// ---------------------------------------------------------------------------

__global__ __launch_bounds__(1024) void decode_kernel(
    const float* __restrict__ ch, const float* __restrict__ wts,
    const ushort4* __restrict__ v2e, const unsigned int* __restrict__ colp32,
    float* __restrict__ out) {
  __shared__ float s_c2v[NE];   // slot-major: [j][check] = [j*NC + c], 96 KB
  __shared__ float s_agg[NV];   // 32 KB

  const int tid = threadIdx.x;
  const int b = blockIdx.x;
  const float* chrow = ch + (size_t)b * NV;

  float chreg[8];
  ushort4 vt[8];
#pragma unroll
  for (int r = 0; r < 8; ++r) {
    chreg[r] = chrow[tid + r * 1024];
    vt[r] = v2e[tid + r * 1024];
  }
  float w[NITER];
#pragma unroll
  for (int i = 0; i < NITER; ++i) w[i] = wts[i];

#pragma unroll
  for (int r = 0; r < 24; ++r) s_c2v[tid + r * 1024] = 0.0f;
  __syncthreads();

  for (int it = 0; it < NITER; ++it) {
    // -------- Phase A: variable update -> s_agg[v] = ch[v] + sum c2v -------
    // Association must match np.add.at: agg = ((c[e1]+c[e2])+c[e3]), then +ch.
#pragma unroll
    for (int r = 0; r < 8; ++r) {
      int v = tid + r * 1024;
      ushort4 t = vt[r];
      float agg = (s_c2v[t.x] + s_c2v[t.y]) + s_c2v[t.z];
      s_agg[v] = chreg[r] + agg;
    }
    __syncthreads();

    const float wi = w[it];

    // -------- Phase B: check update (min-sum with self-exclusion) ----------
#pragma unroll
    for (int r = 0; r < 4; ++r) {
      int c = tid + r * 1024;
      unsigned int w0 = colp32[c];
      unsigned int w1 = colp32[NC + c];
      unsigned int w2 = colp32[2 * NC + c];
      unsigned short col[6];
      col[0] = (unsigned short)(w0 & 0xffffu); col[1] = (unsigned short)(w0 >> 16);
      col[2] = (unsigned short)(w1 & 0xffffu); col[3] = (unsigned short)(w1 >> 16);
      col[4] = (unsigned short)(w2 & 0xffffu); col[5] = (unsigned short)(w2 >> 16);

      float v2c[6];
      unsigned int xs = 0u;
      bool anyz = false;
      float m1 = INFINITY, m2 = INFINITY;
      int imin = 0;
#pragma unroll
      for (int j = 0; j < 6; ++j) {
        float cv = s_c2v[j * NC + c];
        float t = s_agg[col[j]] - cv;
        v2c[j] = t;
        unsigned int u = __float_as_uint(t);
        xs ^= (u & 0x80000000u);
        anyz |= (t == 0.0f);
        float a = fabsf(t);
        if (a < m1) { m2 = m1; m1 = a; imin = j; }
        else if (a < m2) { m2 = a; }
      }
#pragma unroll
      for (int j = 0; j < 6; ++j) {
        float m = (j == imin) ? m2 : m1;
        unsigned int s = xs ^ (__float_as_uint(v2c[j]) & 0x80000000u);
        float o = __uint_as_float(__float_as_uint(m) ^ s) * wi;
        if (anyz) o = 0.0f;
        s_c2v[j * NC + c] = o;
      }
    }
    __syncthreads();
  }

  // -------- Final: out = ch + final aggregate ------------------------------
  float* orow = out + (size_t)b * NV;
#pragma unroll
  for (int r = 0; r < 8; ++r) {
    int v = tid + r * 1024;
    ushort4 t = vt[r];
    float agg = (s_c2v[t.x] + s_c2v[t.y]) + s_c2v[t.z];
    orow[v] = chreg[r] + agg;
  }
}

// ---------------------------------------------------------------------------

extern "C" void kernel_launch(void* const* d_in, const int* in_sizes, int n_in,
                              void* d_out, int out_size, void* d_ws, size_t ws_size,
                              hipStream_t stream) {
  (void)in_sizes; (void)n_in; (void)out_size; (void)ws_size;

  const float* ch   = (const float*)d_in[0];   // [BATCH, NV] f32
  const float* wts  = (const float*)d_in[1];   // [NITER, 1] f32
  const int*  Hcols = (const int*)d_in[3];     // [NE] i32
  float* out = (float*)d_out;

  char* ws = (char*)d_ws;
  int*            cnt     = (int*)(ws + 0);          // 32768 B
  unsigned short* v2e_tmp = (unsigned short*)(ws + 32768);   // 49152 B
  ushort4*        v2e     = (ushort4*)(ws + 81920);          // 65536 B
  unsigned int*   colp32  = (unsigned int*)(ws + 147456);    // 49152 B
  // total ws use: 196608 B

  hipMemsetAsync(cnt, 0, NV * sizeof(int), stream);
  build_v2e<<<(NE + 255) / 256, 256, 0, stream>>>(Hcols, cnt, v2e_tmp);
  sort_transform<<<(NV + 255) / 256, 256, 0, stream>>>(v2e_tmp, v2e);
  pack_cols<<<(NC * 3 + 255) / 256, 256, 0, stream>>>(Hcols, colp32);

  decode_kernel<<<BATCH, 1024, 0, stream>>>(ch, wts, v2e, colp32, out);
}

// Round 3
// 167.308 us; speedup vs baseline: 1.2258x; 1.2258x over previous
//
#include <hip/hip_runtime.h>
#include <stdint.h>

// Problem constants (fixed by the reference)
#define NV    8192   // variables
#define NC    4096   // checks
#define DC    6      // edges per check
#define DV    3      // edges per variable
#define NE    24576  // edges
#define NITER 5
#define BATCH 2048

// ---------------------------------------------------------------------------
// Setup: build per-var sorted edge list, then invert to per-edge slot codes.
// slot(e) = k*NV + var(e), k = rank of e among its var's (ascending) edges.
// Packed planes for coalesced load in decode: slotp[p][c] u32 holds slots of
// edges (6c+2p) and (6c+2p+1).
// ---------------------------------------------------------------------------

__global__ void build_v2e(const int* __restrict__ cols, int* __restrict__ cnt,
                          unsigned short* __restrict__ v2e_tmp) {
  int e = blockIdx.x * blockDim.x + threadIdx.x;
  if (e >= NE) return;
  int v = cols[e];
  int s = atomicAdd(&cnt[v], 1);
  v2e_tmp[v * DV + s] = (unsigned short)e;
}

__global__ void invert_slots(const unsigned short* __restrict__ v2e_tmp,
                             unsigned short* __restrict__ slotp16) {
  int v = blockIdx.x * blockDim.x + threadIdx.x;
  if (v >= NV) return;
  int a = v2e_tmp[v * 3 + 0];
  int b = v2e_tmp[v * 3 + 1];
  int c = v2e_tmp[v * 3 + 2];
  int t;
  if (a > b) { t = a; a = b; b = t; }
  if (b > c) { t = b; b = c; c = t; }
  if (a > b) { t = a; a = b; b = t; }
  int e3[3] = {a, b, c};
#pragma unroll
  for (int k = 0; k < 3; ++k) {
    int e = e3[k];
    int cc = e / DC;
    int j = e - cc * DC;
    // u16 view of u32 plane array: plane j>>1, check cc, half j&1
    slotp16[((j >> 1) * NC + cc) * 2 + (j & 1)] = (unsigned short)(k * NV + v);
  }
}

// ---------------------------------------------------------------------------
// Fused decoder: one workgroup per batch element.
// Single 96 KB LDS array of per-edge message slots, var-major.
// Phase A (contiguous): slot holds c2v -> overwrite with v2c = vl - c2v.
// Phase B (random, reg-preloaded addrs): slot holds v2c -> overwrite with c2v.
// ---------------------------------------------------------------------------

__global__ __launch_bounds__(1024) void decode_kernel(
    const float* __restrict__ ch, const float* __restrict__ wts,
    const unsigned int* __restrict__ slotp, float* __restrict__ out) {
  __shared__ float s_msg[NE];   // 96 KB

  const int tid = threadIdx.x;
  const int b = blockIdx.x;
  const float* chrow = ch + (size_t)b * NV;

  float chreg[8];
#pragma unroll
  for (int r = 0; r < 8; ++r) chreg[r] = chrow[tid + r * 1024];

  float w[NITER];
#pragma unroll
  for (int i = 0; i < NITER; ++i) w[i] = wts[i];

  // Preload the 6 slot element-indices for each of this thread's 4 checks.
  int idx[4][6];
#pragma unroll
  for (int r = 0; r < 4; ++r) {
    int c = tid + r * 1024;
    unsigned int p0 = slotp[c];
    unsigned int p1 = slotp[NC + c];
    unsigned int p2 = slotp[2 * NC + c];
    idx[r][0] = (int)(p0 & 0xFFFFu); idx[r][1] = (int)(p0 >> 16);
    idx[r][2] = (int)(p1 & 0xFFFFu); idx[r][3] = (int)(p1 >> 16);
    idx[r][4] = (int)(p2 & 0xFFFFu); idx[r][5] = (int)(p2 >> 16);
  }

  // ---- Phase A, iteration 0: c2v == 0, so vl = ch, v2c = vl - 0 = ch ------
#pragma unroll
  for (int r = 0; r < 8; ++r) {
    int v = tid + r * 1024;
    float vl = chreg[r];
    s_msg[v] = vl;
    s_msg[NV + v] = vl;
    s_msg[2 * NV + v] = vl;
  }
  __syncthreads();

  for (int it = 0; it < NITER; ++it) {
    const float wi = w[it];

    // ---- Phase B: check update; slots v2c -> c2v ------------------------
#pragma unroll
    for (int r = 0; r < 4; ++r) {
      unsigned int u[6];
      float m1 = INFINITY, m2 = INFINITY;
      unsigned int xs = 0u;
#pragma unroll
      for (int j = 0; j < 6; ++j) {
        float t = s_msg[idx[r][j]];
        unsigned int uu = __float_as_uint(t);
        u[j] = uu;
        xs ^= uu;
        float a = fabsf(t);
        m2 = fminf(m2, fmaxf(m1, a));   // uses OLD m1
        m1 = fminf(m1, a);
      }
      const bool anyz = (m1 == 0.0f);
      const float m1w = m1 * wi;
      const float m2w = m2 * wi;
#pragma unroll
      for (int j = 0; j < 6; ++j) {
        float a = __uint_as_float(u[j] & 0x7FFFFFFFu);
        float mag = (a == m1) ? m2w : m1w;   // ties: m2==m1, identical to ref
        unsigned int s = (xs ^ u[j]) & 0x80000000u;
        float o = __uint_as_float(__float_as_uint(mag) ^ s);
        if (anyz) o = 0.0f;
        s_msg[idx[r][j]] = o;
      }
    }
    __syncthreads();

    // ---- Phase A: variable update; slots c2v -> v2c ---------------------
    if (it < NITER - 1) {
#pragma unroll
      for (int r = 0; r < 8; ++r) {
        int v = tid + r * 1024;
        float c0 = s_msg[v];
        float c1 = s_msg[NV + v];
        float c2 = s_msg[2 * NV + v];
        float vl = chreg[r] + ((c0 + c1) + c2);   // np.add.at association
        s_msg[v] = vl - c0;
        s_msg[NV + v] = vl - c1;
        s_msg[2 * NV + v] = vl - c2;
      }
      __syncthreads();
    }
  }

  // ---- Final: out = ch + sum of final c2v ---------------------------------
  float* orow = out + (size_t)b * NV;
#pragma unroll
  for (int r = 0; r < 8; ++r) {
    int v = tid + r * 1024;
    float c0 = s_msg[v];
    float c1 = s_msg[NV + v];
    float c2 = s_msg[2 * NV + v];
    orow[v] = chreg[r] + ((c0 + c1) + c2);
  }
}

// ---------------------------------------------------------------------------

extern "C" void kernel_launch(void* const* d_in, const int* in_sizes, int n_in,
                              void* d_out, int out_size, void* d_ws, size_t ws_size,
                              hipStream_t stream) {
  (void)in_sizes; (void)n_in; (void)out_size; (void)ws_size;

  const float* ch   = (const float*)d_in[0];   // [BATCH, NV] f32
  const float* wts  = (const float*)d_in[1];   // [NITER, 1] f32
  const int*  Hcols = (const int*)d_in[3];     // [NE] i32
  float* out = (float*)d_out;

  char* ws = (char*)d_ws;
  int*            cnt     = (int*)(ws + 0);                  // 32768 B
  unsigned short* v2e_tmp = (unsigned short*)(ws + 32768);   // 49152 B
  unsigned int*   slotp   = (unsigned int*)(ws + 81920);     // 49152 B
  // total ws use: 131072 B

  hipMemsetAsync(cnt, 0, NV * sizeof(int), stream);
  build_v2e<<<(NE + 255) / 256, 256, 0, stream>>>(Hcols, cnt, v2e_tmp);
  invert_slots<<<(NV + 255) / 256, 256, 0, stream>>>(v2e_tmp, (unsigned short*)slotp);

  decode_kernel<<<BATCH, 1024, 0, stream>>>(ch, wts, slotp, out);
}

// Round 4
// 150.613 us; speedup vs baseline: 1.3617x; 1.1108x over previous
//
#include <hip/hip_runtime.h>
#include <stdint.h>

// Problem constants (fixed by the reference)
#define NV    8192   // variables
#define NC    4096   // checks
#define DC    6      // edges per check
#define DV    3      // edges per variable
#define NE    24576  // edges
#define NITER 5
#define BATCH 2048

// ---------------------------------------------------------------------------
// Setup 1: per-var edge lists (sorted ascending via the 3-way sort below so
// the np.add.at association and slot ranks are deterministic).
// ---------------------------------------------------------------------------

__global__ void build_v2e(const int* __restrict__ cols, int* __restrict__ cnt,
                          unsigned short* __restrict__ v2e_tmp) {
  int e = blockIdx.x * blockDim.x + threadIdx.x;
  if (e >= NE) return;
  int v = cols[e];
  int s = atomicAdd(&cnt[v], 1);
  v2e_tmp[v * DV + s] = (unsigned short)e;
}

// Setup 2: per-edge slot codes, contiguous per check: cslot[e] = k*NV + v,
// where k = rank of edge e among its var's ascending edges. (e = c*6 + j.)
__global__ void invert_slots(const unsigned short* __restrict__ v2e_tmp,
                             unsigned short* __restrict__ cslot) {
  int v = blockIdx.x * blockDim.x + threadIdx.x;
  if (v >= NV) return;
  int a = v2e_tmp[v * 3 + 0];
  int b = v2e_tmp[v * 3 + 1];
  int c = v2e_tmp[v * 3 + 2];
  int t;
  if (a > b) { t = a; a = b; b = t; }
  if (b > c) { t = b; b = c; c = t; }
  if (a > b) { t = a; a = b; b = t; }
  cslot[a] = (unsigned short)(0 * NV + v);
  cslot[b] = (unsigned short)(1 * NV + v);
  cslot[c] = (unsigned short)(2 * NV + v);
}

// ---------------------------------------------------------------------------
// Setup 3: conflict-aware edge schedule. One block (one wave) per group of 64
// consecutive checks (= the checks one decode wave processes in lockstep).
// For each of the 6 LDS instruction rows, greedily (first-fit, LDS-atomic
// auction) pick for every lane an unused edge whose bank (slot%32) has <2
// occupants in this row. Output is BIT-INVARIANT to the permutation chosen
// (check update is exactly order-symmetric), so atomic arbitration order
// cannot affect d_out.
// ---------------------------------------------------------------------------

__global__ __launch_bounds__(64) void greedy_schedule(
    const unsigned short* __restrict__ cslot, unsigned int* __restrict__ slotp) {
  __shared__ unsigned short sl[64][6];
  __shared__ unsigned short pm[64][6];
  __shared__ int cnt[32];

  const int l = threadIdx.x;
  const int c = blockIdx.x * 64 + l;

  const unsigned int* cs32 = (const unsigned int*)cslot;
  unsigned int a0 = cs32[c * 3 + 0];
  unsigned int a1 = cs32[c * 3 + 1];
  unsigned int a2 = cs32[c * 3 + 2];
  sl[l][0] = (unsigned short)(a0 & 0xffffu); sl[l][1] = (unsigned short)(a0 >> 16);
  sl[l][2] = (unsigned short)(a1 & 0xffffu); sl[l][3] = (unsigned short)(a1 >> 16);
  sl[l][4] = (unsigned short)(a2 & 0xffffu); sl[l][5] = (unsigned short)(a2 >> 16);

  unsigned int used = 0;
  for (int j = 0; j < 6; ++j) {
    if (l < 32) cnt[l] = 0;
    __syncthreads();
    int placed = -1;
    for (int k = 0; k < 6; ++k) {
      if (placed >= 0) break;
      if (used & (1u << k)) continue;
      int bk = sl[l][k] & 31;
      int old = atomicAdd(&cnt[bk], 1);
      if (old < 2) placed = k;
      else atomicSub(&cnt[bk], 1);
    }
    if (placed < 0) {  // all remaining banks full: accept a conflict
      for (int k = 0; k < 6; ++k)
        if (!(used & (1u << k))) { placed = k; break; }
    }
    used |= (1u << placed);
    pm[l][j] = sl[l][placed];
    __syncthreads();
  }

  slotp[0 * NC + c] = (unsigned int)pm[l][0] | ((unsigned int)pm[l][1] << 16);
  slotp[1 * NC + c] = (unsigned int)pm[l][2] | ((unsigned int)pm[l][3] << 16);
  slotp[2 * NC + c] = (unsigned int)pm[l][4] | ((unsigned int)pm[l][5] << 16);
}

// ---------------------------------------------------------------------------
// Fused decoder: one workgroup per batch element; 96 KB var-major slot array.
// Phase A (float4-vectorized, contiguous): slots c2v -> v2c = vl - c2v.
// Phase B (random, bank-scheduled rows, reg-preloaded addrs): v2c -> c2v.
// ---------------------------------------------------------------------------

__global__ __launch_bounds__(1024) void decode_kernel(
    const float* __restrict__ ch, const float* __restrict__ wts,
    const unsigned int* __restrict__ slotp, float* __restrict__ out) {
  __shared__ float s_msg[NE];   // 96 KB

  const int tid = threadIdx.x;
  const int b = blockIdx.x;
  const float* chrow = ch + (size_t)b * NV;
  const float4* ch4 = (const float4*)chrow;

  float4 chreg[2];
  chreg[0] = ch4[tid];           // vars 4*tid .. 4*tid+3
  chreg[1] = ch4[1024 + tid];    // vars 4096+4*tid ..

  float w[NITER];
#pragma unroll
  for (int i = 0; i < NITER; ++i) w[i] = wts[i];

  // Preload the 6 (scheduled) slot indices for each of this thread's 4 checks.
  int idx[4][6];
#pragma unroll
  for (int r = 0; r < 4; ++r) {
    int c = tid + r * 1024;
    unsigned int p0 = slotp[c];
    unsigned int p1 = slotp[NC + c];
    unsigned int p2 = slotp[2 * NC + c];
    idx[r][0] = (int)(p0 & 0xFFFFu); idx[r][1] = (int)(p0 >> 16);
    idx[r][2] = (int)(p1 & 0xFFFFu); idx[r][3] = (int)(p1 >> 16);
    idx[r][4] = (int)(p2 & 0xFFFFu); idx[r][5] = (int)(p2 >> 16);
  }

  float4* m0 = (float4*)&s_msg[0];
  float4* m1 = (float4*)&s_msg[NV];
  float4* m2 = (float4*)&s_msg[2 * NV];

  // ---- it=0 Phase A: c2v==0 -> v2c = ch in all 3 planes -------------------
#pragma unroll
  for (int p = 0; p < 2; ++p) {
    int i4 = p * 1024 + tid;
    float4 v = chreg[p];
    m0[i4] = v; m1[i4] = v; m2[i4] = v;
  }
  __syncthreads();

  for (int it = 0; it < NITER; ++it) {
    const float wi = w[it];

    // ---- Phase B: check update; slots v2c -> c2v --------------------------
#pragma unroll
    for (int r = 0; r < 4; ++r) {
      unsigned int u[6];
      float m1v = INFINITY, m2v = INFINITY;
      unsigned int xs = 0u;
#pragma unroll
      for (int j = 0; j < 6; ++j) {
        float t = s_msg[idx[r][j]];
        unsigned int uu = __float_as_uint(t);
        u[j] = uu;
        xs ^= uu;
        float a = fabsf(t);
        m2v = fminf(m2v, fmaxf(m1v, a));   // uses OLD m1v: exact 2nd-min
        m1v = fminf(m1v, a);
      }
      const bool anyz = (m1v == 0.0f);
      const float m1w = m1v * wi;
      const float m2w = m2v * wi;
#pragma unroll
      for (int j = 0; j < 6; ++j) {
        float a = __uint_as_float(u[j] & 0x7FFFFFFFu);
        float mag = (a == m1v) ? m2w : m1w;  // ties: m2v==m1v, matches ref
        unsigned int s = (xs ^ u[j]) & 0x80000000u;
        float o = __uint_as_float(__float_as_uint(mag) ^ s);
        if (anyz) o = 0.0f;
        s_msg[idx[r][j]] = o;
      }
    }
    __syncthreads();

    // ---- Phase A: variable update; slots c2v -> v2c (float4) --------------
    if (it < NITER - 1) {
#pragma unroll
      for (int p = 0; p < 2; ++p) {
        int i4 = p * 1024 + tid;
        float4 c0 = m0[i4], c1 = m1[i4], c2 = m2[i4];
        float4 cr = chreg[p];
        float4 vl;
        vl.x = cr.x + ((c0.x + c1.x) + c2.x);   // np.add.at association
        vl.y = cr.y + ((c0.y + c1.y) + c2.y);
        vl.z = cr.z + ((c0.z + c1.z) + c2.z);
        vl.w = cr.w + ((c0.w + c1.w) + c2.w);
        float4 o0 = {vl.x - c0.x, vl.y - c0.y, vl.z - c0.z, vl.w - c0.w};
        float4 o1 = {vl.x - c1.x, vl.y - c1.y, vl.z - c1.z, vl.w - c1.w};
        float4 o2 = {vl.x - c2.x, vl.y - c2.y, vl.z - c2.z, vl.w - c2.w};
        m0[i4] = o0; m1[i4] = o1; m2[i4] = o2;
      }
      __syncthreads();
    }
  }

  // ---- Final: out = ch + ((c0+c1)+c2), float4 stores ----------------------
  float4* orow4 = (float4*)(out + (size_t)b * NV);
#pragma unroll
  for (int p = 0; p < 2; ++p) {
    int i4 = p * 1024 + tid;
    float4 c0 = m0[i4], c1 = m1[i4], c2 = m2[i4];
    float4 cr = chreg[p];
    float4 o;
    o.x = cr.x + ((c0.x + c1.x) + c2.x);
    o.y = cr.y + ((c0.y + c1.y) + c2.y);
    o.z = cr.z + ((c0.z + c1.z) + c2.z);
    o.w = cr.w + ((c0.w + c1.w) + c2.w);
    orow4[i4] = o;
  }
}

// ---------------------------------------------------------------------------

extern "C" void kernel_launch(void* const* d_in, const int* in_sizes, int n_in,
                              void* d_out, int out_size, void* d_ws, size_t ws_size,
                              hipStream_t stream) {
  (void)in_sizes; (void)n_in; (void)out_size; (void)ws_size;

  const float* ch   = (const float*)d_in[0];   // [BATCH, NV] f32
  const float* wts  = (const float*)d_in[1];   // [NITER, 1] f32
  const int*  Hcols = (const int*)d_in[3];     // [NE] i32
  float* out = (float*)d_out;

  char* ws = (char*)d_ws;
  int*            cnt     = (int*)(ws + 0);                  // 32768 B
  unsigned short* v2e_tmp = (unsigned short*)(ws + 32768);   // 49152 B
  unsigned short* cslot   = (unsigned short*)(ws + 81920);   // 49152 B
  unsigned int*   slotp   = (unsigned int*)(ws + 131072);    // 49152 B
  // total ws use: 180224 B

  hipMemsetAsync(cnt, 0, NV * sizeof(int), stream);
  build_v2e<<<(NE + 255) / 256, 256, 0, stream>>>(Hcols, cnt, v2e_tmp);
  invert_slots<<<(NV + 255) / 256, 256, 0, stream>>>(v2e_tmp, cslot);
  greedy_schedule<<<NC / 64, 64, 0, stream>>>(cslot, slotp);

  decode_kernel<<<BATCH, 1024, 0, stream>>>(ch, wts, slotp, out);
}